// Round 1
// 719.796 us; speedup vs baseline: 1.0760x; 1.0760x over previous
//
#include <hip/hip_runtime.h>
#include <stdint.h>

// ---------------- problem constants ----------------
#define B_N   1024
#define D_N   512
#define C_N   50000
#define K_N   3
#define CPAD  50048              // classes padded to multiple of 64
#define NROWS (CPAD * 4)         // 200192 padded weight rows (4 = K padded)

#define S_SCALE 50.0f
#define COS_M   0.8775825619f  // cos(0.5)
#define SIN_M   0.4794255386f  // sin(0.5)
#define EPS_C   1e-7f

typedef __bf16 bf16_t;
typedef bf16_t bf16x8 __attribute__((ext_vector_type(8)));
typedef float  f32x4  __attribute__((ext_vector_type(4)));

__device__ __forceinline__ float wave_reduce_sum(float v) {
#pragma unroll
    for (int m = 1; m < 64; m <<= 1) v += __shfl_xor(v, m, 64);
    return v;
}

__device__ __forceinline__ void async_copy16(const void* g, void* l) {
    __builtin_amdgcn_global_load_lds(
        (const __attribute__((address_space(1))) void*)g,
        (__attribute__((address_space(3))) void*)l,
        16, 0, 0);
}

// ---------------- prepass: normalize embeddings -> bf16 ----------------
// one wave per row, 4 rows/block, grid 256
__global__ void k_norm_emb(const float* __restrict__ x, bf16_t* __restrict__ y) {
    const int row  = blockIdx.x * 4 + (threadIdx.x >> 6);
    const int lane = threadIdx.x & 63;
    const float4* p = (const float4*)(x + (size_t)row * D_N + lane * 8);
    float4 a = p[0], b = p[1];
    float s = a.x*a.x + a.y*a.y + a.z*a.z + a.w*a.w
            + b.x*b.x + b.y*b.y + b.z*b.z + b.w*b.w;
    s = wave_reduce_sum(s);
    float sc = 1.0f / fmaxf(sqrtf(s), 1e-12f);
    bf16x8 o;
    o[0] = (bf16_t)(a.x * sc); o[1] = (bf16_t)(a.y * sc);
    o[2] = (bf16_t)(a.z * sc); o[3] = (bf16_t)(a.w * sc);
    o[4] = (bf16_t)(b.x * sc); o[5] = (bf16_t)(b.y * sc);
    o[6] = (bf16_t)(b.z * sc); o[7] = (bf16_t)(b.w * sc);
    *(bf16x8*)(y + (size_t)row * D_N + lane * 8) = o;
}

// ---------------- prepass: normalize weight rows -> bf16, K padded 3->4 ----------------
// 4 rows per wave (ILP across independent reduce chains), 16 rows/block, grid 9375
__global__ void k_norm_w(const float* __restrict__ x, bf16_t* __restrict__ y) {
    const int w    = threadIdx.x >> 6;
    const int lane = threadIdx.x & 63;
    const int base = blockIdx.x * 16 + w * 4;
#pragma unroll
    for (int i = 0; i < 4; ++i) {
        const int row = base + i;
        const float4* p = (const float4*)(x + (size_t)row * D_N + lane * 8);
        float4 a = p[0], b = p[1];
        float s = a.x*a.x + a.y*a.y + a.z*a.z + a.w*a.w
                + b.x*b.x + b.y*b.y + b.z*b.z + b.w*b.w;
        s = wave_reduce_sum(s);
        float sc = 1.0f / fmaxf(sqrtf(s), 1e-12f);
        const size_t orow = (size_t)row + (size_t)(row / 3);  // padded row index
        bf16x8 o;
        o[0] = (bf16_t)(a.x * sc); o[1] = (bf16_t)(a.y * sc);
        o[2] = (bf16_t)(a.z * sc); o[3] = (bf16_t)(a.w * sc);
        o[4] = (bf16_t)(b.x * sc); o[5] = (bf16_t)(b.y * sc);
        o[6] = (bf16_t)(b.z * sc); o[7] = (bf16_t)(b.w * sc);
        *(bf16x8*)(y + orow * D_N + lane * 8) = o;
    }
}

// ---------------- main GEMM: 256x256 tile, BK=64, 8-phase counted-vmcnt ----------------
// A = padded weight rows (class*4+k), B = batch. 8 waves (2M x 4N), each wave
// owns 128 rows x 64 batches. LDS: 2 buffers x {A0,A1,B0,B1} half-tiles of
// 128x64 bf16 (16KB each) = 128KB. Staging via global_load_lds with
// pre-swizzled SOURCE (linear LDS dest); reads apply byte ^= (row&7)<<4.
// C/D layout (16x16x32): col=lane&15 (batch), row=quad*4+reg -> reg = subcenter.
__global__ __launch_bounds__(512, 2) void k_gemm8(const bf16_t* __restrict__ Wn,
                                                  const bf16_t* __restrict__ En,
                                                  const int*    __restrict__ labels,
                                                  float*        __restrict__ out) {
    __shared__ __align__(16) char smem[131072];

    const int tid  = threadIdx.x;
    const int w    = tid >> 6;          // wave 0..7
    const int lane = tid & 63;
    const int wm   = w >> 2;            // M half owner (128 rows)
    const int wn   = w & 3;             // N quarter owner (64 batches)
    const int cl   = lane & 15;
    const int quad = lane >> 4;

    // bijective XCD swizzle: 3128 = 8 * 391 (weight panel's 4 batch-tiles -> same XCD)
    const int lid   = blockIdx.x;
    const int nid   = (lid & 7) * 391 + (lid >> 3);
    const int btile = nid & 3;
    const int wtile = nid >> 2;
    const int b0    = btile * 256;
    const size_t r0 = (size_t)wtile * 256;

    // staging: per-lane pre-swizzled source offset; LDS dest stays linear
    const int   srcswz = (((lane & 7) ^ (lane >> 3)) << 4);
    const int   srow   = w * 8 + (lane >> 3);       // row within half (j=0)
    const char* Wb = (const char*)Wn;
    const char* Eb = (const char*)En;

    auto stageA = [&](int tile, int h) {
        char* l = smem + (tile & 1) * 65536 + h * 16384 + w * 1024;
        const char* g = Wb + ((r0 + (size_t)(h * 128 + srow)) << 10) + tile * 128 + srcswz;
        async_copy16(g, l);
        async_copy16(g + (64 << 10), l + 8192);
    };
    auto stageB = [&](int tile, int h) {
        char* l = smem + (tile & 1) * 65536 + 32768 + h * 16384 + w * 1024;
        const char* g = Eb + ((size_t)(b0 + h * 128 + srow) << 10) + tile * 128 + srcswz;
        async_copy16(g, l);
        async_copy16(g + (64 << 10), l + 8192);
    };

    // fragment read offsets, XOR-swizzled (row&7 == lane&7 for all fragment rows)
    const int off0 = cl * 128 + ((      quad * 16) ^ ((lane & 7) << 4));   // ks=0
    const int off1 = cl * 128 + ((64 +  quad * 16) ^ ((lane & 7) << 4));   // ks=1

    f32x4  acc[8][4] = {};
    bf16x8 a[4][2], b[4][2];

    // ---- prologue: B0(0) B1(0) A0(0) A1(0) | B0(1) B1(1) A0(1) ----
    stageB(0, 0); stageB(0, 1); stageA(0, 0); stageA(0, 1);
    asm volatile("s_waitcnt vmcnt(4)" ::: "memory");
    stageB(1, 0); stageB(1, 1); stageA(1, 0);
    asm volatile("s_waitcnt vmcnt(6)" ::: "memory");
    __builtin_amdgcn_s_barrier();

#define MFMA_QUAD(MB, NB)                                                        \
    _Pragma("unroll")                                                            \
    for (int mf = 0; mf < 4; ++mf) {                                             \
        _Pragma("unroll")                                                        \
        for (int nf = 0; nf < 2; ++nf) {                                         \
            acc[(MB)*4+mf][(NB)*2+nf] = __builtin_amdgcn_mfma_f32_16x16x32_bf16( \
                a[mf][0], b[(NB)*2+nf][0], acc[(MB)*4+mf][(NB)*2+nf], 0, 0, 0);  \
            acc[(MB)*4+mf][(NB)*2+nf] = __builtin_amdgcn_mfma_f32_16x16x32_bf16( \
                a[mf][1], b[(NB)*2+nf][1], acc[(MB)*4+mf][(NB)*2+nf], 0, 0, 0);  \
        }                                                                        \
    }

#pragma unroll 2
    for (int t = 0; t < 8; ++t) {
        const char* Ab = smem + (t & 1) * 65536 + wm * 16384;
        const char* Bb = smem + (t & 1) * 65536 + 32768 + (wn >> 1) * 16384 + (wn & 1) * 8192;

        // ---- P1: read A-MH0 + all B; stage A1(t+1); MFMA MH0 x {n0,n1} ----
#pragma unroll
        for (int mf = 0; mf < 4; ++mf) {
            a[mf][0] = *(const bf16x8*)(Ab + mf * 2048 + off0);
            a[mf][1] = *(const bf16x8*)(Ab + mf * 2048 + off1);
        }
#pragma unroll
        for (int nf = 0; nf < 4; ++nf) {
            b[nf][0] = *(const bf16x8*)(Bb + nf * 2048 + off0);
            b[nf][1] = *(const bf16x8*)(Bb + nf * 2048 + off1);
        }
        if (t < 7) stageA(t + 1, 1);
        __builtin_amdgcn_s_barrier();
        __builtin_amdgcn_s_setprio(1);
        MFMA_QUAD(0, 0)
        __builtin_amdgcn_s_setprio(0);
        __builtin_amdgcn_s_barrier();

        // ---- P2: stage B0(t+2); MFMA MH0 x {n2,n3} ----
        if (t < 6) stageB(t + 2, 0);
        __builtin_amdgcn_s_barrier();
        __builtin_amdgcn_s_setprio(1);
        MFMA_QUAD(0, 1)
        __builtin_amdgcn_s_setprio(0);
        __builtin_amdgcn_s_barrier();

        // ---- P3: read A-MH1; stage B1(t+2); MFMA MH1 x {n2,n3} ----
#pragma unroll
        for (int mf = 0; mf < 4; ++mf) {
            a[mf][0] = *(const bf16x8*)(Ab + 8192 + mf * 2048 + off0);
            a[mf][1] = *(const bf16x8*)(Ab + 8192 + mf * 2048 + off1);
        }
        if (t < 6) stageB(t + 2, 1);
        __builtin_amdgcn_s_barrier();
        __builtin_amdgcn_s_setprio(1);
        MFMA_QUAD(1, 1)
        __builtin_amdgcn_s_setprio(0);
        __builtin_amdgcn_s_barrier();

        // ---- P4: stage A0(t+2); MFMA MH1 x {n0,n1}; counted vmcnt ----
        if (t < 6) stageA(t + 2, 0);
        __builtin_amdgcn_s_barrier();
        __builtin_amdgcn_s_setprio(1);
        MFMA_QUAD(1, 0)
        __builtin_amdgcn_s_setprio(0);
        if (t < 6)       { asm volatile("s_waitcnt vmcnt(6)" ::: "memory"); }
        else if (t == 6) { asm volatile("s_waitcnt vmcnt(0)" ::: "memory"); }
        __builtin_amdgcn_s_barrier();
    }
#undef MFMA_QUAD

    // ---- epilogue: subcenter max (regs 0..2), margin, LDS transpose, store ----
    float* So = (float*)smem;   // [256][65]
    int lab[4];
#pragma unroll
    for (int n = 0; n < 4; ++n) lab[n] = labels[b0 + wn * 64 + n * 16 + cl];

    const int cb = wtile * 64;
#pragma unroll
    for (int m = 0; m < 8; ++m) {
        const int cls_l = wm * 32 + (m >> 2) * 16 + (m & 3) * 4 + quad;
        const int c = cb + cls_l;
#pragma unroll
        for (int n = 0; n < 4; ++n) {
            float v = fmaxf(fmaxf(acc[m][n][0], acc[m][n][1]), acc[m][n][2]);
            if (c == lab[n]) {
                float x = fminf(fmaxf(v, -1.0f + EPS_C), 1.0f - EPS_C);
                v = x * COS_M - sqrtf(fmaxf(1.0f - x * x, 0.0f)) * SIN_M;
            }
            So[(wn * 64 + n * 16 + cl) * 65 + cls_l] = S_SCALE * v;
        }
    }
    __syncthreads();

    const int row  = tid >> 1;          // batch-local 0..255
    const int half = tid & 1;
    float*       gp = out + (size_t)(b0 + row) * C_N + cb + half * 32;
    const float* sp = So + row * 65 + half * 32;
#pragma unroll
    for (int q = 0; q < 8; ++q) {
        const int c = cb + half * 32 + q * 4;
        if (c < C_N) {
            float4 o = make_float4(sp[q*4+0], sp[q*4+1], sp[q*4+2], sp[q*4+3]);
            *(float4*)(gp + q * 4) = o;
        }
    }
}

// ---------------- fallback path (ws too small for bf16 weights) ----------------
__global__ void k_fb_norms(const float* __restrict__ emb, const float* __restrict__ w,
                           float* __restrict__ einv, float* __restrict__ winv) {
    const int row  = blockIdx.x * 4 + (threadIdx.x >> 6);
    const int lane = threadIdx.x & 63;
    if (row >= B_N + C_N * K_N) return;
    const float* src = (row < B_N) ? (emb + (size_t)row * D_N)
                                   : (w + (size_t)(row - B_N) * D_N);
    const float4* p = (const float4*)(src + lane * 8);
    float4 a = p[0], b = p[1];
    float s = a.x*a.x + a.y*a.y + a.z*a.z + a.w*a.w
            + b.x*b.x + b.y*b.y + b.z*b.z + b.w*b.w;
    s = wave_reduce_sum(s);
    if (lane == 0) {
        float sc = 1.0f / fmaxf(sqrtf(s), 1e-12f);
        if (row < B_N) einv[row] = sc; else winv[row - B_N] = sc;
    }
}

__global__ void k_fb_gemm(const float* __restrict__ emb, const float* __restrict__ w,
                          const int* __restrict__ labels, const float* __restrict__ einv,
                          const float* __restrict__ winv, float* __restrict__ out) {
    const int b = blockIdx.x;
    const int c = blockIdx.y * 256 + threadIdx.x;
    if (c >= C_N) return;
    const float4* e4 = (const float4*)(emb + (size_t)b * D_N);
    const float es = einv[b];
    float best = -1e30f;
    for (int k = 0; k < K_N; ++k) {
        const float4* w4 = (const float4*)(w + ((size_t)c * K_N + k) * D_N);
        float dot = 0.0f;
#pragma unroll 4
        for (int d = 0; d < D_N / 4; ++d) {
            float4 a = e4[d], bb = w4[d];
            dot += a.x*bb.x + a.y*bb.y + a.z*bb.z + a.w*bb.w;
        }
        dot *= es * winv[c * K_N + k];
        best = fmaxf(best, dot);
    }
    if (c == labels[b]) {
        float x = fminf(fmaxf(best, -1.0f + EPS_C), 1.0f - EPS_C);
        best = x * COS_M - sqrtf(fmaxf(1.0f - x * x, 0.0f)) * SIN_M;
    }
    out[(size_t)b * C_N + c] = S_SCALE * best;
}

// ---------------- launch ----------------
extern "C" void kernel_launch(void* const* d_in, const int* in_sizes, int n_in,
                              void* d_out, int out_size, void* d_ws, size_t ws_size,
                              hipStream_t stream) {
    const float* emb    = (const float*)d_in[0];
    const int*   labels = (const int*)d_in[1];
    const float* weight = (const float*)d_in[2];
    float*       out    = (float*)d_out;

    const size_t offW = (size_t)1 << 20;                      // 1 MB for En
    const size_t need = offW + (size_t)NROWS * D_N * 2;       // + bf16 weights
    if (ws_size >= need) {
        bf16_t* En = (bf16_t*)d_ws;
        bf16_t* Wn = (bf16_t*)((char*)d_ws + offW);
        k_norm_emb<<<B_N / 4, 256, 0, stream>>>(emb, En);
        k_norm_w<<<(C_N * K_N) / 16, 256, 0, stream>>>(weight, Wn);
        k_gemm8<<<dim3(3128), 512, 0, stream>>>(Wn, En, labels, out);
    } else {
        float* einv = (float*)d_ws;
        float* winv = einv + B_N;
        k_fb_norms<<<(B_N + C_N * K_N) / 4, 256, 0, stream>>>(emb, weight, einv, winv);
        k_fb_gemm<<<dim3(B_N, (C_N + 255) / 256), 256, 0, stream>>>(emb, weight, labels,
                                                                    einv, winv, out);
    }
}